// Round 3
// baseline (807.189 us; speedup 1.0000x reference)
//
#include <hip/hip_runtime.h>
#include <stdint.h>

#define BATCH 8
#define NH 12
#define SL 4096
#define HD 64
#define NL 64
#define SEG 64
#define BHN (BATCH*NH)      // 96
#define NCHUNK 4
#define CHUNK (SL/NCHUNK)   // 1024
#define SCALE 0.35355339059327373f  // 1/sqrt(sqrt(64))

typedef unsigned short bfu;

__device__ __forceinline__ float bf2f(bfu u) { return __uint_as_float(((unsigned)u) << 16); }
__device__ __forceinline__ bfu f2bf(float f) {
    unsigned u = __float_as_uint(f);
    u += 0x7fffu + ((u >> 16) & 1u);   // round-to-nearest-even
    return (bfu)(u >> 16);
}

// dtype-adaptive loads: f32 flag selects float vs bf16 interpretation
__device__ __forceinline__ float ld1(const void* p, size_t i, int f32) {
    return f32 ? ((const float*)p)[i] : bf2f(((const bfu*)p)[i]);
}
__device__ __forceinline__ void ld4(const void* p, size_t i, int f32, float o[4]) {
    if (f32) {
        float4 v = *(const float4*)((const float*)p + i);
        o[0] = v.x; o[1] = v.y; o[2] = v.z; o[3] = v.w;
    } else {
        ushort4 v = *(const ushort4*)((const bfu*)p + i);
        o[0] = bf2f(v.x); o[1] = bf2f(v.y); o[2] = bf2f(v.z); o[3] = bf2f(v.w);
    }
}

// C[4x4] += A[4*tr+i][k] * B[k][4*tc+j], 64-deep, A pitch PA, B pitch PB (floats)
template<int PA, int PB>
__device__ __forceinline__ void mm64(const float* A, const float* B, float acc[4][4], int tr, int tc) {
#pragma unroll
    for (int k4 = 0; k4 < 16; ++k4) {
        alignas(16) float a[4][4];
#pragma unroll
        for (int i = 0; i < 4; ++i)
            *(float4*)(&a[i][0]) = *(const float4*)(A + (4*tr + i)*PA + 4*k4);
#pragma unroll
        for (int kk = 0; kk < 4; ++kk) {
            float4 b = *(const float4*)(B + (4*k4 + kk)*PB + 4*tc);
#pragma unroll
            for (int i = 0; i < 4; ++i) {
                acc[i][0] = fmaf(a[i][kk], b.x, acc[i][0]);
                acc[i][1] = fmaf(a[i][kk], b.y, acc[i][1]);
                acc[i][2] = fmaf(a[i][kk], b.z, acc[i][2]);
                acc[i][3] = fmaf(a[i][kk], b.w, acc[i][3]);
            }
        }
    }
}

// ---------------- Stage 0: dtype detect (mask is all-ones) ----------------
__global__ void detect_k(const void* __restrict__ M, int* __restrict__ dflag) {
    if (threadIdx.x == 0) {
        unsigned v = *(const unsigned*)M;          // f32 1.0 = 0x3F800000 ; bf16 pair = 0x3F803F80
        dflag[0] = (v == 0x3F800000u) ? 1 : 0;
    }
}

// ---------------- Stage A: landmark means ----------------
__global__ __launch_bounds__(64) void landmarks_k(const void* __restrict__ Q, const void* __restrict__ K,
                                                  const void* __restrict__ M, const int* __restrict__ dt,
                                                  float* __restrict__ Ql, float* __restrict__ KlT) {
    int f32 = dt[0];
    int bh = blockIdx.x, l = blockIdx.y, d = threadIdx.x;
    int b = bh / NH;
    size_t qb = ((size_t)(bh*SL) + l*SEG)*HD + d;
    size_t mb = (size_t)b*SL + l*SEG;
    float aq = 0.f, ak = 0.f;
#pragma unroll 8
    for (int i = 0; i < SEG; ++i) {
        float mk = ld1(M, mb + i, f32);
        aq += ld1(Q, qb + (size_t)i*HD, f32) * mk;
        ak += ld1(K, qb + (size_t)i*HD, f32) * mk;
    }
    float sc = SCALE / (float)SEG;
    Ql[(bh*NL + l)*HD + d] = aq * sc;
    KlT[bh*NL*HD + d*NL + l] = ak * sc;
}

// ---------------- Stage B: kernel_2 softmax + per-bh colsum max ----------------
__global__ __launch_bounds__(256) void k2_kernel(const float* __restrict__ Ql, const float* __restrict__ KlT,
                                                 float* __restrict__ K2, float* __restrict__ cmax) {
    __shared__ float Qs[64*68];
    __shared__ float Bs[64*64];
    __shared__ float Cs[64*68];
    int bh = blockIdx.x, t = threadIdx.x;
    int tr = t >> 4, tc = t & 15;
    for (int idx = t; idx < 4096; idx += 256) {
        int r = idx >> 6, c = idx & 63;
        Qs[r*68 + c] = Ql[(bh*64 + r)*64 + c];
        Bs[idx] = KlT[bh*4096 + idx];
    }
    __syncthreads();
    float acc[4][4] = {};
    mm64<68,64>(Qs, Bs, acc, tr, tc);
#pragma unroll
    for (int i = 0; i < 4; ++i)
        *(float4*)&Cs[(4*tr + i)*68 + 4*tc] = make_float4(acc[i][0], acc[i][1], acc[i][2], acc[i][3]);
    __syncthreads();
    if (t < 64) {
        float mx = -1e30f;
        for (int m = 0; m < 64; ++m) mx = fmaxf(mx, Cs[t*68 + m]);
        float s = 0.f;
        for (int m = 0; m < 64; ++m) { float e = __expf(Cs[t*68 + m] - mx); Cs[t*68 + m] = e; s += e; }
        float r = 1.f / s;
        for (int m = 0; m < 64; ++m) Cs[t*68 + m] *= r;
    }
    __syncthreads();
    for (int idx = t; idx < 4096; idx += 256) {
        int r = idx >> 6, c = idx & 63;
        K2[bh*4096 + idx] = Cs[r*68 + c];
    }
    if (t < 64) {
        float cs = 0.f;
        for (int l = 0; l < 64; ++l) cs += Cs[l*68 + t];
        for (int off = 32; off > 0; off >>= 1) cs = fmaxf(cs, __shfl_xor(cs, off, 64));
        if (t == 0) cmax[bh] = cs;
    }
}

// ---------------- Stage D: kernel_3 @ V, split-K flash partials ----------------
__global__ __launch_bounds__(256) void k3v_partial(const void* __restrict__ K, const void* __restrict__ V,
                                                   const void* __restrict__ M, const int* __restrict__ dt,
                                                   const float* __restrict__ Ql,
                                                   float* __restrict__ Opart, float* __restrict__ mpart,
                                                   float* __restrict__ lpart) {
    __shared__ float Qls[64*68];
    __shared__ float Bbuf[64*64];    // KsT (transposed) then V (row-major)
    __shared__ float P[64*68];
    __shared__ float bias[64];
    __shared__ float alpha_s[64];
    __shared__ float mrow[64], lrow[64];
    int f32 = dt[0];
    int bh = blockIdx.x, ch = blockIdx.y;
    int b = bh / NH;
    int t = threadIdx.x, tr = t >> 4, tc = t & 15;

    for (int idx = t; idx < 4096; idx += 256) {
        int r = idx >> 6, c = idx & 63;
        Qls[r*68 + c] = Ql[(bh*64 + r)*64 + c];
    }
    if (t < 64) { mrow[t] = -1e38f; lrow[t] = 0.f; }
    float Oacc[4][4] = {};
    __syncthreads();

    int s0 = ch * CHUNK;
    for (int st = 0; st < CHUNK/64; ++st) {
        int sbase = s0 + st*64;
        __syncthreads();   // S0: prior PV (reads P, Bbuf) complete
        for (int g = t; g < 1024; g += 256) {
            int j = g >> 4, d4 = (g & 15) << 2;
            float v[4];
            ld4(K, ((size_t)(bh*SL) + sbase + j)*HD + d4, f32, v);
            float mk = ld1(M, (size_t)b*SL + sbase + j, f32) * SCALE;
            Bbuf[(d4+0)*64 + j] = v[0] * mk;
            Bbuf[(d4+1)*64 + j] = v[1] * mk;
            Bbuf[(d4+2)*64 + j] = v[2] * mk;
            Bbuf[(d4+3)*64 + j] = v[3] * mk;
        }
        if (t < 64) bias[t] = -1000000000.0f * (1.f - ld1(M, (size_t)b*SL + sbase + t, f32));
        __syncthreads();   // S1: KsT ready
        float la[4][4] = {};
        mm64<68,64>(Qls, Bbuf, la, tr, tc);
#pragma unroll
        for (int i = 0; i < 4; ++i)
#pragma unroll
            for (int j = 0; j < 4; ++j) la[i][j] += bias[4*tc + j];
#pragma unroll
        for (int i = 0; i < 4; ++i)
            *(float4*)&P[(4*tr + i)*68 + 4*tc] = make_float4(la[i][0], la[i][1], la[i][2], la[i][3]);
        __syncthreads();   // S2: logits in P, Bbuf reads done
        if (t < 64) {
            float mloc = -1e30f;
            for (int j = 0; j < 64; ++j) mloc = fmaxf(mloc, P[t*68 + j]);
            float mold = mrow[t];
            float mnew = fmaxf(mold, mloc);
            float al = __expf(mold - mnew);   // mold=-1e38 -> 0
            float s = 0.f;
            for (int j = 0; j < 64; ++j) { float e = __expf(P[t*68 + j] - mnew); P[t*68 + j] = e; s += e; }
            lrow[t] = lrow[t]*al + s;
            mrow[t] = mnew;
            alpha_s[t] = al;
        } else {
            for (int g = t - 64; g < 1024; g += 192) {
                int j = g >> 4, d4 = (g & 15) << 2;
                float v[4];
                ld4(V, ((size_t)(bh*SL) + sbase + j)*HD + d4, f32, v);
                *(float4*)&Bbuf[j*64 + d4] = make_float4(v[0], v[1], v[2], v[3]);
            }
        }
        __syncthreads();   // S3: softmax + V ready
        float al[4];
#pragma unroll
        for (int i = 0; i < 4; ++i) al[i] = alpha_s[4*tr + i];
#pragma unroll
        for (int i = 0; i < 4; ++i)
#pragma unroll
            for (int j = 0; j < 4; ++j) Oacc[i][j] *= al[i];
        mm64<68,64>(P, Bbuf, Oacc, tr, tc);
    }
    __syncthreads();
    int pc = bh*NCHUNK + ch;
    if (t < 64) { mpart[pc*64 + t] = mrow[t]; lpart[pc*64 + t] = lrow[t]; }
#pragma unroll
    for (int i = 0; i < 4; ++i)
        *(float4*)&Opart[(size_t)pc*4096 + (4*tr + i)*64 + 4*tc] =
            make_float4(Oacc[i][0], Oacc[i][1], Oacc[i][2], Oacc[i][3]);
}

// ---------------- Stage D2: combine partials -> k3V ----------------
__global__ __launch_bounds__(256) void combine_k(const float* __restrict__ Opart, const float* __restrict__ mpart,
                                                 const float* __restrict__ lpart, float* __restrict__ K3V) {
    __shared__ float coef[NCHUNK][64];
    int bh = blockIdx.x, t = threadIdx.x;
    if (t < 64) {
        float mg = -1e38f;
        for (int ch = 0; ch < NCHUNK; ++ch) mg = fmaxf(mg, mpart[(bh*NCHUNK + ch)*64 + t]);
        float e[NCHUNK];
        float sg = 0.f;
        for (int ch = 0; ch < NCHUNK; ++ch) {
            e[ch] = __expf(mpart[(bh*NCHUNK + ch)*64 + t] - mg);
            sg += e[ch] * lpart[(bh*NCHUNK + ch)*64 + t];
        }
        float r = 1.f / fmaxf(sg, 1e-37f);
        for (int ch = 0; ch < NCHUNK; ++ch) coef[ch][t] = e[ch] * r;
    }
    __syncthreads();
    int c = t & 63, lq = t >> 6;
    for (int k = 0; k < 16; ++k) {
        int l = 4*k + lq;
        float s = 0.f;
#pragma unroll
        for (int ch = 0; ch < NCHUNK; ++ch)
            s += coef[ch][l] * Opart[(size_t)(bh*NCHUNK + ch)*4096 + l*64 + c];
        K3V[(bh*64 + l)*64 + c] = s;
    }
}

// ---------------- Stage C: iterative inverse (6 Newton-Schulz) + W = Vi @ k3V ----------------
__global__ __launch_bounds__(256) void inv_kernel(const float* __restrict__ K2, const float* __restrict__ cmaxArr,
                                                  const float* __restrict__ K3V, float* __restrict__ W) {
    __shared__ float Km[4096];
    __shared__ float Vi[4096];
    __shared__ float B1[4096];
    __shared__ float B2[4096];
    int bh = blockIdx.x, t = threadIdx.x, tr = t >> 4, tc = t & 15;
    float cm = 0.f;
    for (int i = 0; i < BHN; ++i) cm = fmaxf(cm, cmaxArr[i]);
    float rc = 1.f / fmaxf(cm, 1e-37f);
    for (int idx = t; idx < 4096; idx += 256) Km[idx] = K2[bh*4096 + idx];
    __syncthreads();
    for (int idx = t; idx < 4096; idx += 256) {
        int i = idx >> 6, j = idx & 63;
        Vi[idx] = Km[j*64 + i] * rc;
    }
    __syncthreads();
    float acc[4][4];
    for (int it = 0; it < 6; ++it) {
        // B1 = Km @ Vi (=KV)
#pragma unroll
        for (int i = 0; i < 4; ++i) for (int j = 0; j < 4; ++j) acc[i][j] = 0.f;
        mm64<64,64>(Km, Vi, acc, tr, tc);
#pragma unroll
        for (int i = 0; i < 4; ++i)
            *(float4*)&B1[(4*tr + i)*64 + 4*tc] = make_float4(acc[i][0], acc[i][1], acc[i][2], acc[i][3]);
        __syncthreads();
        // B2 = 7*B1 - B1@B1
#pragma unroll
        for (int i = 0; i < 4; ++i) for (int j = 0; j < 4; ++j) acc[i][j] = 0.f;
        mm64<64,64>(B1, B1, acc, tr, tc);
#pragma unroll
        for (int i = 0; i < 4; ++i)
#pragma unroll
            for (int j = 0; j < 4; ++j) acc[i][j] = 7.f*B1[(4*tr + i)*64 + 4*tc + j] - acc[i][j];
#pragma unroll
        for (int i = 0; i < 4; ++i)
            *(float4*)&B2[(4*tr + i)*64 + 4*tc] = make_float4(acc[i][0], acc[i][1], acc[i][2], acc[i][3]);
        __syncthreads();
        // B2 = 15*B1 - B1@B2  (in-place, reg roundtrip)
#pragma unroll
        for (int i = 0; i < 4; ++i) for (int j = 0; j < 4; ++j) acc[i][j] = 0.f;
        mm64<64,64>(B1, B2, acc, tr, tc);
#pragma unroll
        for (int i = 0; i < 4; ++i)
#pragma unroll
            for (int j = 0; j < 4; ++j) acc[i][j] = 15.f*B1[(4*tr + i)*64 + 4*tc + j] - acc[i][j];
        __syncthreads();   // all reads of B2 done
#pragma unroll
        for (int i = 0; i < 4; ++i)
            *(float4*)&B2[(4*tr + i)*64 + 4*tc] = make_float4(acc[i][0], acc[i][1], acc[i][2], acc[i][3]);
        __syncthreads();
        // Vi = 3.25*Vi - 0.25*(Vi @ B2)
#pragma unroll
        for (int i = 0; i < 4; ++i) for (int j = 0; j < 4; ++j) acc[i][j] = 0.f;
        mm64<64,64>(Vi, B2, acc, tr, tc);
        __syncthreads();   // all reads of Vi done
#pragma unroll
        for (int i = 0; i < 4; ++i)
#pragma unroll
            for (int j = 0; j < 4; ++j) {
                int off = (4*tr + i)*64 + 4*tc + j;
                Vi[off] = 3.25f*Vi[off] - 0.25f*acc[i][j];
            }
        __syncthreads();
    }
    // W = Vi @ K3V
    for (int idx = t; idx < 4096; idx += 256) B1[idx] = K3V[bh*4096 + idx];
    __syncthreads();
#pragma unroll
    for (int i = 0; i < 4; ++i) for (int j = 0; j < 4; ++j) acc[i][j] = 0.f;
    mm64<64,64>(Vi, B1, acc, tr, tc);
#pragma unroll
    for (int i = 0; i < 4; ++i)
        *(float4*)&W[(bh*64 + 4*tr + i)*64 + 4*tc] = make_float4(acc[i][0], acc[i][1], acc[i][2], acc[i][3]);
}

// ---------------- Stage F: X = softmax(Qs @ Kl^T) @ W ----------------
__global__ __launch_bounds__(256) void final_k(const void* __restrict__ Q, const void* __restrict__ M,
                                               const int* __restrict__ dt,
                                               const float* __restrict__ KlT, const float* __restrict__ W,
                                               void* __restrict__ X) {
    __shared__ float QP[64*68];   // Q tile, then P (logits/softmax)
    __shared__ float Bs[64*64];   // KlT
    __shared__ float Ws[64*64];   // W
    int f32 = dt[0];
    int bh = blockIdx.x, tile = blockIdx.y;
    int b = bh / NH;
    int t = threadIdx.x, tr = t >> 4, tc = t & 15;
    int s0 = tile * 64;
    for (int g = t; g < 1024; g += 256) {
        int r = g >> 4, d4 = (g & 15) << 2;
        float v[4];
        ld4(Q, ((size_t)(bh*SL) + s0 + r)*HD + d4, f32, v);
        float mk = ld1(M, (size_t)b*SL + s0 + r, f32) * SCALE;
        QP[r*68 + d4 + 0] = v[0] * mk;
        QP[r*68 + d4 + 1] = v[1] * mk;
        QP[r*68 + d4 + 2] = v[2] * mk;
        QP[r*68 + d4 + 3] = v[3] * mk;
    }
    for (int idx = t; idx < 4096; idx += 256) {
        Bs[idx] = KlT[bh*4096 + idx];
        Ws[idx] = W[bh*4096 + idx];
    }
    __syncthreads();
    float acc[4][4] = {};
    mm64<68,64>(QP, Bs, acc, tr, tc);
    __syncthreads();   // all Q-tile reads done before aliasing with P
#pragma unroll
    for (int i = 0; i < 4; ++i)
        *(float4*)&QP[(4*tr + i)*68 + 4*tc] = make_float4(acc[i][0], acc[i][1], acc[i][2], acc[i][3]);
    __syncthreads();
    if (t < 64) {
        float mx = -1e30f;
        for (int l = 0; l < 64; ++l) mx = fmaxf(mx, QP[t*68 + l]);
        float s = 0.f;
        for (int l = 0; l < 64; ++l) { float e = __expf(QP[t*68 + l] - mx); QP[t*68 + l] = e; s += e; }
        float r = 1.f / s;
        for (int l = 0; l < 64; ++l) QP[t*68 + l] *= r;
    }
    __syncthreads();
    float o[4][4] = {};
    mm64<68,64>(QP, Ws, o, tr, tc);
#pragma unroll
    for (int i = 0; i < 4; ++i) {
        size_t base = ((size_t)(bh*SL) + s0 + 4*tr + i)*HD + 4*tc;
        if (f32) {
            *(float4*)((float*)X + base) = make_float4(o[i][0], o[i][1], o[i][2], o[i][3]);
        } else {
            ushort4 w;
            w.x = f2bf(o[i][0]); w.y = f2bf(o[i][1]); w.z = f2bf(o[i][2]); w.w = f2bf(o[i][3]);
            *(ushort4*)((bfu*)X + base) = w;
        }
    }
}

extern "C" void kernel_launch(void* const* d_in, const int* in_sizes, int n_in,
                              void* d_out, int out_size, void* d_ws, size_t ws_size,
                              hipStream_t stream) {
    const void* Q = d_in[0];
    const void* K = d_in[1];
    const void* V = d_in[2];
    const void* M = d_in[3];
    float* ws = (float*)d_ws;
    size_t o = 0;
    int*   dflag = (int*)(ws + o); o += 64;
    float* Ql    = ws + o; o += (size_t)BHN*64*64;
    float* KlT   = ws + o; o += (size_t)BHN*64*64;
    float* K2    = ws + o; o += (size_t)BHN*64*64;
    float* K3V   = ws + o; o += (size_t)BHN*64*64;
    float* W     = ws + o; o += (size_t)BHN*64*64;
    float* mpart = ws + o; o += (size_t)BHN*NCHUNK*64;
    float* lpart = ws + o; o += (size_t)BHN*NCHUNK*64;
    float* cmax  = ws + o; o += 128;
    float* Opart = ws + o; o += (size_t)BHN*NCHUNK*64*64;   // biggest buffer last

    detect_k<<<1, 64, 0, stream>>>(M, dflag);
    landmarks_k<<<dim3(BHN, NL), 64, 0, stream>>>(Q, K, M, dflag, Ql, KlT);
    k2_kernel<<<BHN, 256, 0, stream>>>(Ql, KlT, K2, cmax);
    k3v_partial<<<dim3(BHN, NCHUNK), 256, 0, stream>>>(K, V, M, dflag, Ql, Opart, mpart, lpart);
    combine_k<<<BHN, 256, 0, stream>>>(Opart, mpart, lpart, K3V);
    inv_kernel<<<BHN, 256, 0, stream>>>(K2, cmax, K3V, W);
    final_k<<<dim3(BHN, SL/64), 256, 0, stream>>>(Q, M, dflag, KlT, W, d_out);
}